// Round 10
// baseline (881.557 us; speedup 1.0000x reference)
//
#include <hip/hip_runtime.h>
#include <stdint.h>

// ---------------- types ----------------
typedef __attribute__((ext_vector_type(8))) short bf16x8;   // 8 x bf16 = 4 VGPRs
typedef __attribute__((ext_vector_type(4))) short s16x4;    // 4 x bf16 = 8B
typedef __attribute__((ext_vector_type(4))) float f32x4;
typedef __attribute__((ext_vector_type(4))) unsigned u32x4;

#define AS1 __attribute__((address_space(1)))
#define AS3 __attribute__((address_space(3)))

static __device__ __forceinline__ void gload_lds16(const void* g, void* l) {
  __builtin_amdgcn_global_load_lds((const AS1 unsigned int*)g,
                                   (AS3 unsigned int*)l, 16, 0, 0);
}

// round-to-nearest-even f32 -> bf16 bits
static __device__ __forceinline__ short f2bs(float f) {
  unsigned u = __builtin_bit_cast(unsigned, f);
  unsigned r = (u + 0x7fffu + ((u >> 16) & 1u)) >> 16;
  return (short)r;
}
static __device__ __forceinline__ float bs2f(short s) {
  unsigned u = ((unsigned)(unsigned short)s) << 16;
  return __builtin_bit_cast(float, u);
}

static __device__ __forceinline__ float sigmoid_f(float x) {
  return 1.0f / (1.0f + __expf(-x));
}
static __device__ __forceinline__ float tanh_f(float x) {
  float ax = fabsf(x);
  float e  = __expf(-2.0f * ax);
  float t  = (1.0f - e) / (1.0f + e);
  return copysignf(t, x);
}

// constants
#define BATCH 256
#define HID   512
#define STEPS 256
#define G3    1536   // 3*HID

// ---------------- fp32 -> bf16 convert (weights) ----------------
__global__ __launch_bounds__(256) void convert_kernel(const float* __restrict__ src,
                                                      short* __restrict__ dst, int n4) {
  int i = blockIdx.x * 256 + threadIdx.x;
  if (i < n4) {
    float4 v = *(const float4*)(src + (size_t)i * 4);
    s16x4 o;
    o[0] = f2bs(v.x); o[1] = f2bs(v.y); o[2] = f2bs(v.z); o[3] = f2bs(v.w);
    *(s16x4*)(dst + (size_t)i * 4) = o;
  }
}

// ---------------- x[b][i][s] f32  ->  xT[s][b][i] bf16 ----------------
__global__ __launch_bounds__(256) void transpose_kernel(const float* __restrict__ x,
                                                        short* __restrict__ xT) {
  int bx = blockIdx.x;
  int st = bx & 7, it = (bx >> 3) & 15, b = bx >> 7;
  int s0 = st * 32, i0 = it * 32;
  int tid = threadIdx.x;
  __shared__ float tile[32][33];
  int il = tid >> 3, s4 = (tid & 7) * 4;
  float4 v = *(const float4*)(x + (size_t)b * 131072 + (size_t)(i0 + il) * 256 + s0 + s4);
  tile[il][s4 + 0] = v.x; tile[il][s4 + 1] = v.y;
  tile[il][s4 + 2] = v.z; tile[il][s4 + 3] = v.w;
  __syncthreads();
  int sl = tid >> 3, iv = (tid & 7) * 4;
  s16x4 o;
  o[0] = f2bs(tile[iv + 0][sl]); o[1] = f2bs(tile[iv + 1][sl]);
  o[2] = f2bs(tile[iv + 2][sl]); o[3] = f2bs(tile[iv + 3][sl]);
  *(s16x4*)(xT + (size_t)(s0 + sl) * 131072 + (size_t)b * 512 + i0 + iv) = o;
}

// ---------------- phase 1: gi[m][g] = xT[m] . W_ih[g] + bias_ih[g] (bf16 out) ----
// R10: DOUBLE-BUFFERED STAGING with counted vmcnt (T3 minimal 2-phase recipe).
// R9 post-mortem: the bank-conflict fix (kept — verified correct) moved
// nothing -> phase1 was latency-bound, not LDS-bound: the single-buffer
// structure drained vmcnt(0) at every iteration's barrier, exposing the full
// LLC load latency x16 iters (the m102 small-N collapse regime; K=512 has no
// amortization). Now: STAGE(next buf) -> s_waitcnt vmcnt(4) (waits only the
// PREVIOUS iteration's 4 staging loads, issued a full iteration earlier ->
// latency hides under MFMA) -> barrier -> frag reads -> lgkmcnt(0)+barrier
// (read-release: my reads retired before anyone's next STAGE overwrites) ->
// MFMA. vmcnt never 0 in the loop (only final iter). vmcnt arithmetic is
// exact: the staging loads are this wave's only VMEM ops in the loop.
__global__ __launch_bounds__(256) void phase1_kernel(const short* __restrict__ A,
                                                     const short* __restrict__ B,
                                                     const float* __restrict__ bias,
                                                     short* __restrict__ out, int M) {
  int MT = M >> 7;
  int bx = blockIdx.x;
  int mt = bx % MT, nt = bx / MT;
  int m0 = mt * 128, n0 = nt * 128;
  int tid = threadIdx.x, w = tid >> 6, lane = tid & 63;
  int lm = lane & 15, q = lane >> 4;
  int wm = w & 1, wn = w >> 1;
  __shared__ short As[2][128 * 32];
  __shared__ short Bs[2][128 * 32];
  f32x4 acc[4][4] = {};
  // pre-swizzled source lane (R9, verified): flip block-bit0 with bit3,
  // bit1 with bit4 -> content lands swizzled; frag reads apply the same
  // involution -> conflict-free ds_read_b128.
  int slsw = lane ^ ((lane >> 3) & 1) ^ (((lane >> 4) & 1) << 1);
  int srow = slsw >> 2;
  int scol = (slsw & 3) * 8;
  int i_0 = w * 2, i_1 = w * 2 + 1;
  const short* a0p = A + (size_t)(m0 + i_0 * 16 + srow) * 512 + scol;
  const short* a1p = A + (size_t)(m0 + i_1 * 16 + srow) * 512 + scol;
  const short* b0p = B + (size_t)(n0 + i_0 * 16 + srow) * 512 + scol;
  const short* b1p = B + (size_t)(n0 + i_1 * 16 + srow) * 512 + scol;

#define STAGE(bb, kt) do {                                   \
    gload_lds16(a0p + (kt) * 32, &As[bb][i_0 * 512]);        \
    gload_lds16(a1p + (kt) * 32, &As[bb][i_1 * 512]);        \
    gload_lds16(b0p + (kt) * 32, &Bs[bb][i_0 * 512]);        \
    gload_lds16(b1p + (kt) * 32, &Bs[bb][i_1 * 512]);        \
  } while (0)

  STAGE(0, 0);
  int cur = 0;
  for (int kt = 0; kt < 16; ++kt) {
    if (kt < 15) {
      STAGE(cur ^ 1, kt + 1);
      // wait for buf[cur]'s 4 loads (older than the 4 just issued)
      asm volatile("s_waitcnt vmcnt(4)" ::: "memory");
    } else {
      asm volatile("s_waitcnt vmcnt(0)" ::: "memory");
    }
    // acquire: all waves' buf[cur] staging visible
    asm volatile("s_barrier" ::: "memory");
    __builtin_amdgcn_sched_barrier(0);

    bf16x8 av[4], bv[4];
#pragma unroll
    for (int f = 0; f < 4; ++f) {
      int Sa = (wm * 64 + f * 16 + lm) * 32 + q * 8;
      Sa ^= (Sa >> 3) & 0x18;          // read-side involution (shorts)
      int Sb = (wn * 64 + f * 16 + lm) * 32 + q * 8;
      Sb ^= (Sb >> 3) & 0x18;
      av[f] = *(const bf16x8*)(&As[cur][0] + Sa);
      bv[f] = *(const bf16x8*)(&Bs[cur][0] + Sb);
    }
    // release: my frag reads retired (lgkmcnt(0)) -> after the barrier no
    // wave can still be reading buf[cur] when the next STAGE overwrites it
    asm volatile("s_waitcnt lgkmcnt(0)\n\ts_barrier" ::: "memory");
    __builtin_amdgcn_sched_barrier(0);

#pragma unroll
    for (int fm = 0; fm < 4; ++fm)
#pragma unroll
      for (int fn = 0; fn < 4; ++fn)
        acc[fm][fn] = __builtin_amdgcn_mfma_f32_16x16x32_bf16(av[fm], bv[fn], acc[fm][fn], 0, 0, 0);
    cur ^= 1;
  }
#undef STAGE
#pragma unroll
  for (int fn = 0; fn < 4; ++fn) {
    int g = n0 + wn * 64 + fn * 16 + lm;
    float bi = bias[g];
#pragma unroll
    for (int fm = 0; fm < 4; ++fm) {
      int rb = m0 + wm * 64 + fm * 16 + q * 4;
#pragma unroll
      for (int r = 0; r < 4; ++r)
        out[(size_t)(rb + r) * G3 + g] = f2bs(acc[fm][fn][r] + bi);
    }
  }
}

// ---------------- phase 2: persistent GRU scan ----------------
// EXACT R6 kernel (measured 533-538us scan; best verified). R8 proved the
// poll cadence is LLC-CONTENTION-LIMITED (~8.4MB/round across 256 blocks):
// doubling cadence doubled coherent-load demand past LLC saturation and
// REGRESSED 1.8x. This protocol (tagged-dword publish, single-bundle poll
// with s_sleep(1) pacing, raw lgkmcnt-only barriers) is the measured optimum
// of the family; scan is at its structural floor (~2.1us/step = ~1.5 detect
// + ~0.6 tail).
// Protocol: dword = {bf16 h << 16 | step tag}; dword stores single-copy
// atomic so value+tag never tear. Publishes of tag t+1 happen only after the
// barrier following all waves' polls of t -> any visible tag-t+2 word implies
// every block passed poll(t); parity double buffer covers reuse.
__global__ __launch_bounds__(256) void scan_kernel(const short* __restrict__ gi,
                                                   const short* __restrict__ Whh,
                                                   const float* __restrict__ bias_hh,
                                                   unsigned* __restrict__ hbuf,
                                                   float* __restrict__ hmaster,
                                                   int CH, int step_base, int first) {
  int bid = blockIdx.x;
  int xcd = bid & 7, slot = bid >> 3;
  int group = xcd + 8 * (slot >> 4);
  int j = slot & 15;
  int tid = threadIdx.x;
  int w = tid >> 6, lane = tid & 63;
  int lm = lane & 15, q = lane >> 4;
  int grow = group * 16;

  __shared__ short h_lds[16 * 520];      // padded rows: 512+8
  __shared__ float gh_lds[16][100];
  __shared__ float h_loc[512];           // [16][32] fp32 master slice
  __shared__ float bhh[96];

  // W_hh slice into registers: wave w (<3) -> gate w, 2 N-tiles of 16
  bf16x8 Bf[2][16];
  if (w < 3) {
#pragma unroll
    for (int tau = 0; tau < 2; ++tau)
#pragma unroll
      for (int kt = 0; kt < 16; ++kt) {
        int row = w * 512 + j * 32 + tau * 16 + lm;
        Bf[tau][kt] = *(const bf16x8*)(Whh + (size_t)row * 512 + kt * 32 + q * 8);
      }
  }

  if (tid < 96) {
    int p = tid >> 5, cc = tid & 31;
    bhh[tid] = bias_hh[p * 512 + j * 32 + cc];
  }
#pragma unroll
  for (int u = 0; u < 2; ++u) {
    int idx = tid + u * 256;
    int r = idx >> 5, cc = idx & 31;
    h_loc[idx] = first ? 0.0f : hmaster[(size_t)(grow + r) * 512 + j * 32 + cc];
  }
  __syncthreads();

  // per-thread gi pointers (2 elements per thread per gate), bf16
  int i0 = tid, i1 = tid + 256;
  const short* gp0 = gi + (size_t)(grow + (i0 >> 5)) * G3 + j * 32 + (i0 & 31);
  const short* gp1 = gi + (size_t)(grow + (i1 >> 5)) * G3 + j * 32 + (i1 & 31);
  const size_t gstride = (size_t)256 * G3;

  // software prefetch (plain cached loads; rides across raw barriers)
  short pg0r = gp0[0], pg0z = gp0[512], pg0n = gp0[1024];
  short pg1r = gp1[0], pg1z = gp1[512], pg1n = gp1[1024];

  // poll geometry: this block reads the group's full h (16 rows x 512 cols of
  // tagged dwords = 8192 words). Thread covers 8 chunks of 16B:
  //   word f = tid*4 + c*1024  ->  row = (tid>>7) + 2c, col = (tid&127)*4
  unsigned o0 = (unsigned)tid * 16u;          // byte offset of chunk 0
  const int r0 = tid >> 7;
  const int colb = (tid & 127) * 4;
  short* lp = h_lds + r0 * 520 + colb;        // +c*1040 shorts per chunk (2 rows)
  unsigned* grp_base = hbuf + (size_t)group * 8192;

  for (int t = 0; t < CH; ++t) {
    int gstep = step_base + t;
    int p = gstep & 1;
    const unsigned* src = grp_base + (size_t)p * 131072;
    unsigned want = (unsigned)gstep;

    // ---- poll: load all 8 chunks (sc0 sc1, waitcnt INSIDE the asm so the
    // tag check can never be hoisted above the wait), retry until every word
    // of this thread's share carries tag==gstep. Bounded: wrong beats hang.
    u32x4 v0, v1, v2, v3, v4, v5, v6, v7;
    int spin = 0;
    for (;;) {
      asm volatile(
          "global_load_dwordx4 %0, %8, %16 sc0 sc1\n\t"
          "global_load_dwordx4 %1, %9, %16 sc0 sc1\n\t"
          "global_load_dwordx4 %2, %10, %16 sc0 sc1\n\t"
          "global_load_dwordx4 %3, %11, %16 sc0 sc1\n\t"
          "global_load_dwordx4 %4, %12, %16 sc0 sc1\n\t"
          "global_load_dwordx4 %5, %13, %16 sc0 sc1\n\t"
          "global_load_dwordx4 %6, %14, %16 sc0 sc1\n\t"
          "global_load_dwordx4 %7, %15, %16 sc0 sc1\n\t"
          "s_waitcnt vmcnt(0)"
          : "=&v"(v0), "=&v"(v1), "=&v"(v2), "=&v"(v3),
            "=&v"(v4), "=&v"(v5), "=&v"(v6), "=&v"(v7)
          : "v"(o0), "v"(o0 + 4096u), "v"(o0 + 8192u), "v"(o0 + 12288u),
            "v"(o0 + 16384u), "v"(o0 + 20480u), "v"(o0 + 24576u), "v"(o0 + 28672u),
            "s"(src)
          : "memory");
      unsigned d;
      d  = (v0[0] ^ want) | (v0[1] ^ want) | (v0[2] ^ want) | (v0[3] ^ want);
      d |= (v1[0] ^ want) | (v1[1] ^ want) | (v1[2] ^ want) | (v1[3] ^ want);
      d |= (v2[0] ^ want) | (v2[1] ^ want) | (v2[2] ^ want) | (v2[3] ^ want);
      d |= (v3[0] ^ want) | (v3[1] ^ want) | (v3[2] ^ want) | (v3[3] ^ want);
      d |= (v4[0] ^ want) | (v4[1] ^ want) | (v4[2] ^ want) | (v4[3] ^ want);
      d |= (v5[0] ^ want) | (v5[1] ^ want) | (v5[2] ^ want) | (v5[3] ^ want);
      d |= (v6[0] ^ want) | (v6[1] ^ want) | (v6[2] ^ want) | (v6[3] ^ want);
      d |= (v7[0] ^ want) | (v7[1] ^ want) | (v7[2] ^ want) | (v7[3] ^ want);
      if (((d & 0xffffu) == 0u) || (++spin > (1 << 16))) break;
      __builtin_amdgcn_s_sleep(1);
    }

    // stash fresh h (strip tags) straight into the MFMA staging layout
#define STASH(vv, c)                                                         \
    {                                                                        \
      s16x4 o_;                                                              \
      o_[0] = (short)(vv[0] >> 16); o_[1] = (short)(vv[1] >> 16);            \
      o_[2] = (short)(vv[2] >> 16); o_[3] = (short)(vv[3] >> 16);            \
      *(s16x4*)(lp + (c) * 1040) = o_;                                       \
    }
    STASH(v0, 0) STASH(v1, 1) STASH(v2, 2) STASH(v3, 3)
    STASH(v4, 4) STASH(v5, 5) STASH(v6, 6) STASH(v7, 7)
#undef STASH

    // consume current gi prefetch; issue next step's (rides across barriers)
    float cg0r = bs2f(pg0r), cg0z = bs2f(pg0z), cg0n = bs2f(pg0n);
    float cg1r = bs2f(pg1r), cg1z = bs2f(pg1z), cg1n = bs2f(pg1n);
    {
      size_t o = (size_t)((t + 1 < CH) ? (t + 1) : t) * gstride;
      pg0r = gp0[o]; pg0z = gp0[o + 512]; pg0n = gp0[o + 1024];
      pg1r = gp1[o]; pg1z = gp1[o + 512]; pg1n = gp1[o + 1024];
    }
    // raw barrier #1: LDS ordering only (h_lds stash -> MFMA reads);
    // no vmcnt drain, so gi prefetch + publish stores ride across.
    asm volatile("s_waitcnt lgkmcnt(0)\n\ts_barrier" ::: "memory");
    __builtin_amdgcn_sched_barrier(0);

    // MFMA: gh[16 x 32] for this wave's gate; 4 independent acc chains
    if (w < 3) {
      f32x4 a0 = {0.f,0.f,0.f,0.f}, a1 = {0.f,0.f,0.f,0.f};
      f32x4 a2 = {0.f,0.f,0.f,0.f}, a3 = {0.f,0.f,0.f,0.f};
#pragma unroll
      for (int kt = 0; kt < 8; ++kt) {
        bf16x8 a = *(const bf16x8*)(h_lds + lm * 520 + kt * 32 + q * 8);
        a0 = __builtin_amdgcn_mfma_f32_16x16x32_bf16(a, Bf[0][kt], a0, 0, 0, 0);
        a1 = __builtin_amdgcn_mfma_f32_16x16x32_bf16(a, Bf[1][kt], a1, 0, 0, 0);
      }
#pragma unroll
      for (int kt = 8; kt < 16; ++kt) {
        bf16x8 a = *(const bf16x8*)(h_lds + lm * 520 + kt * 32 + q * 8);
        a2 = __builtin_amdgcn_mfma_f32_16x16x32_bf16(a, Bf[0][kt], a2, 0, 0, 0);
        a3 = __builtin_amdgcn_mfma_f32_16x16x32_bf16(a, Bf[1][kt], a3, 0, 0, 0);
      }
#pragma unroll
      for (int r = 0; r < 4; ++r) {
        gh_lds[q * 4 + r][w * 32 + lm]      = a0[r] + a2[r];
        gh_lds[q * 4 + r][w * 32 + 16 + lm] = a1[r] + a3[r];
      }
    }
    // raw barrier #2: LDS ordering only (gh_lds writes -> cell reads)
    asm volatile("s_waitcnt lgkmcnt(0)\n\ts_barrier" ::: "memory");
    __builtin_amdgcn_sched_barrier(0);

    // elementwise GRU cell + immediate tagged publish (own values only —
    // h_lds/gh_lds hazards are covered by the barriers bracketing the next
    // iteration's phases)
    unsigned tagp = (unsigned)(gstep + 1);
    unsigned* dstb = grp_base + (size_t)(1 - p) * 131072;
    {
      int r = i0 >> 5, cc = i0 & 31;
      float hr = gh_lds[r][cc]      + bhh[cc];
      float hz = gh_lds[r][32 + cc] + bhh[32 + cc];
      float hn = gh_lds[r][64 + cc] + bhh[64 + cc];
      float rr = sigmoid_f(cg0r + hr);
      float zz = sigmoid_f(cg0z + hz);
      float nn = tanh_f(cg0n + rr * hn);
      float hv = (1.0f - zz) * nn + zz * h_loc[i0];
      h_loc[i0] = hv;
      unsigned val = (((unsigned)(unsigned short)f2bs(hv)) << 16) | tagp;
      unsigned* dp = dstb + r * 512 + j * 32 + cc;
      asm volatile("global_store_dword %0, %1, off sc0 sc1" :: "v"(dp), "v"(val) : "memory");
    }
    {
      int r = i1 >> 5, cc = i1 & 31;
      float hr = gh_lds[r][cc]      + bhh[cc];
      float hz = gh_lds[r][32 + cc] + bhh[32 + cc];
      float hn = gh_lds[r][64 + cc] + bhh[64 + cc];
      float rr = sigmoid_f(cg1r + hr);
      float zz = sigmoid_f(cg1z + hz);
      float nn = tanh_f(cg1n + rr * hn);
      float hv = (1.0f - zz) * nn + zz * h_loc[i1];
      h_loc[i1] = hv;
      unsigned val = (((unsigned)(unsigned short)f2bs(hv)) << 16) | tagp;
      unsigned* dp = dstb + r * 512 + j * 32 + cc;
      asm volatile("global_store_dword %0, %1, off sc0 sc1" :: "v"(dp), "v"(val) : "memory");
    }
  }

  // write fp32 state back (d_out doubles as h_master across chunk launches)
#pragma unroll
  for (int u = 0; u < 2; ++u) {
    int idx = tid + u * 256;
    int r = idx >> 5, cc = idx & 31;
    hmaster[(size_t)(grow + r) * 512 + j * 32 + cc] = h_loc[idx];
  }
}

// ---------------- host ----------------
extern "C" void kernel_launch(void* const* d_in, const int* in_sizes, int n_in,
                              void* d_out, int out_size, void* d_ws, size_t ws_size,
                              hipStream_t stream) {
  const float* x   = (const float*)d_in[0];
  const float* Wih = (const float*)d_in[1];
  const float* Whh = (const float*)d_in[2];
  const float* bih = (const float*)d_in[3];
  const float* bhh = (const float*)d_in[4];
  float* out = (float*)d_out;
  char* ws = (char*)d_ws;

  const size_t XT_BYTES   = (size_t)256 * 256 * 512 * 2;  // 64 MiB
  const size_t W_BYTES    = (size_t)1536 * 512 * 2;       // 1.5 MiB
  const size_t HBUF_BYTES = (size_t)2 * 256 * 512 * 4;    // 1 MiB (tagged dwords)
  const size_t FIXED = XT_BYTES + 2 * W_BYTES + HBUF_BYTES + 4096;

  int CH = 256;
  while (CH > 4 && FIXED + (size_t)CH * 256 * G3 * 2 > ws_size) CH >>= 1;

  size_t off = 0;
  short* gi = (short*)(ws + off);          off += (size_t)CH * 256 * G3 * 2;
  short* xT = (short*)(ws + off);          off += XT_BYTES;
  short* WihB = (short*)(ws + off);        off += W_BYTES;
  short* WhhB = (short*)(ws + off);        off += W_BYTES;
  unsigned* hbuf = (unsigned*)(ws + off);

  hipMemsetAsync(hbuf, 0, HBUF_BYTES, stream);

  convert_kernel<<<768, 256, 0, stream>>>(Wih, WihB, 196608);
  convert_kernel<<<768, 256, 0, stream>>>(Whh, WhhB, 196608);
  transpose_kernel<<<32768, 256, 0, stream>>>(x, xT);

  int nch = 256 / CH;
  for (int c = 0; c < nch; ++c) {
    int M = CH * 256;
    phase1_kernel<<<(M / 128) * 12, 256, 0, stream>>>(
        xT + (size_t)c * CH * 256 * 512, WihB, bih, gi, M);
    scan_kernel<<<256, 256, 0, stream>>>(gi, WhhB, bhh, hbuf, out,
                                         CH, c * CH, c == 0 ? 1 : 0);
  }
}